// Round 9
// baseline (1752.121 us; speedup 1.0000x reference)
//
#include <hip/hip_runtime.h>
#include <cstdint>
#include <cstddef>

// BooleanReservoir — persistent cooperative kernel, v8 (2-hop all-to-all barrier).
// lane = batch; states[node] = u64 (bit b = batch b). Packed LUT + adjacency in
// LDS. Never-reused ring (129 slots): publishes are agent-scope stores, gathers
// are PLAIN cached loads (L2-deduped; R8 proved FETCH == LUT-only).
// R9 change: barrier = 64 contiguous u32 arrival counters (4 lines). Arrive =
// one atomicAdd; EVERY block's wave 0 polls all 64 with one 64-lane sc1 load and
// checks __all(v >= 4(s+1)). 2 hops (arrive -> observe) vs R8's 4-hop central
// scan+go chain with two polling-quantization penalties.

#define N_NODES   20000
#define N_INPUT   64
#define K_MAX     12
#define T_STEPS   128
#define N_BATCH   64
#define N_OUT     10
#define N_FEAT    (N_NODES - N_INPUT)   // 19936
#define DUMMY_NODE 20000                // always-zero state word
#define ST_STRIDE 20008                 // words/slot, 64B-aligned
#define R_DEPTH   (T_STEPS + 1)         // 129 slots, write-once

#define NBLK 256
#define NTHR 1024                       // 16 waves/block, 1 block/CU
#define NPB  78                         // nodes/block: 256*78 = 19968 >= 19936
#define NPB_PAD 80
#define BAR_N 64                        // arrival counters (contiguous, 4 lines)

typedef unsigned long long u64;

#define A_LOAD(p)    __hip_atomic_load((p), __ATOMIC_RELAXED, __HIP_MEMORY_SCOPE_AGENT)
#define A_STORE(p,v) __hip_atomic_store((p), (v), __ATOMIC_RELAXED, __HIP_MEMORY_SCOPE_AGENT)
#define A_RMW(p,v)   __hip_atomic_fetch_add((p), (v), __ATOMIC_RELAXED, __HIP_MEMORY_SCOPE_AGENT)

// ---------------- pack x: xp[t][b] = bits j of x[b][t][j] ----------------
__global__ __launch_bounds__(256) void pack_x_kernel(const int* __restrict__ x,
                                                     u64* __restrict__ xp) {
  const int t = blockIdx.x;
  const int wave = threadIdx.x >> 6, lane = threadIdx.x & 63;
  for (int b = wave; b < N_BATCH; b += 4) {
    int v = x[((size_t)b * T_STEPS + t) * 64 + lane];
    u64 bal = __ballot(v != 0);
    if (lane == 0) xp[(size_t)t * N_BATCH + b] = bal;
  }
}

// -------- init ring slot 0, per-slot dummy words, wcol, arrival counters --------
__global__ __launch_bounds__(256) void init_kernel(const int* __restrict__ inis,
                                                   const int* __restrict__ w_in,
                                                   u64* __restrict__ ring,
                                                   u64* __restrict__ wcol,
                                                   unsigned* __restrict__ arr) {
  if (blockIdx.x < 79) {
    int n = blockIdx.x * 256 + threadIdx.x;
    if (n >= N_INPUT && n < N_NODES)
      ring[n] = (inis[n] != 0) ? ~0ull : 0ull;         // slot 0 state
  } else {
    const int wave = threadIdx.x >> 6, lane = threadIdx.x & 63;
    for (int i = wave; i < 64; i += 4) {
      int wv = w_in[(size_t)lane * 64 + i];            // lane = j
      u64 wc = __ballot(wv != 0);
      if (lane == 0) wcol[i] = wc;
    }
    // dummy word (always 0) in every slot; pads never read
    if (threadIdx.x < R_DEPTH)
      ring[(size_t)threadIdx.x * ST_STRIDE + DUMMY_NODE] = 0ull;
    if (threadIdx.x < BAR_N) arr[threadIdx.x] = 0u;    // ws re-poisoned each call
  }
}

// -------- precompute u(t): u_all[t*64+i] bit b = (xp[t][b] & wcol[i]) != 0 --------
__global__ __launch_bounds__(64) void u_pre_kernel(const u64* __restrict__ xp,
                                                   const u64* __restrict__ wcol,
                                                   u64* __restrict__ u_all) {
  const int t = blockIdx.x, lane = threadIdx.x;
  u64 xw = xp[(size_t)t * N_BATCH + lane];             // lane = batch
  for (int i = 0; i < 64; i++) {
    u64 ub = __ballot((xw & wcol[i]) != 0);
    if (lane == 0) u_all[(size_t)t * 64 + i] = ub;
  }
}

// ---- 64x64 bit transpose: lane l holds row l; returns lane b holding column b ----
__device__ __forceinline__ u64 bit_transpose64(u64 w, int lane) {
  const u64 LO0 = 0x00000000FFFFFFFFull, LO1 = 0x0000FFFF0000FFFFull,
            LO2 = 0x00FF00FF00FF00FFull, LO3 = 0x0F0F0F0F0F0F0F0Full,
            LO4 = 0x3333333333333333ull, LO5 = 0x5555555555555555ull;
#define XP_STAGE(d, LO)                                                  \
  {                                                                      \
    u64 p = (u64)__shfl_xor((long long)w, (d), 64);                      \
    if (lane & (d)) w = ((p >> (d)) & (LO)) | (w & ~(LO));               \
    else            w = (w & (LO)) | ((p << (d)) & ~(LO));               \
  }
  XP_STAGE(32, LO0) XP_STAGE(16, LO1) XP_STAGE(8, LO2)
  XP_STAGE(4,  LO3) XP_STAGE(2,  LO4) XP_STAGE(1, LO5)
#undef XP_STAGE
  return w;
}

// ---------------- persistent reservoir: all 128 steps ----------------
__global__ __launch_bounds__(NTHR) void reservoir_kernel(
    const int* __restrict__ lut, const int* __restrict__ adj,
    const int* __restrict__ mask, const int* __restrict__ inis,
    const u64* __restrict__ u_all, u64* __restrict__ ring,
    unsigned* __restrict__ arr) {
  __shared__ u64 lut_lds[NPB_PAD * 64];        // 40960 B
  __shared__ int adj_lds[NPB_PAD * K_MAX];     //  3840 B
  __shared__ unsigned char hn_lds[NPB_PAD];

  const int bi = blockIdx.x;
  const int tid = threadIdx.x;
  const int wave = tid >> 6, lane = tid & 63;
  const int base = N_INPUT + bi * NPB;
  const int nloc = min(NPB, N_NODES - base);   // last block: 46

  // one-time cache scrub: drop poison/prior-iteration lines from L1/L2 so all
  // later PLAIN ring/u_all loads fetch fresh post-publish data (R2 lesson:
  // per-step cache ops serialize; once per block is free).
  if (wave == 0) __builtin_amdgcn_fence(__ATOMIC_ACQUIRE, "agent");

  // ---- prologue: adjacency (slot-REVERSED: slot j at offset 11-j) + hn ----
  if (tid < NPB_PAD) {
    int i = tid, h = 0;
    if (i < nloc) {
      for (int j = 0; j < K_MAX; j++) {
        int m = mask[(size_t)(base + i) * K_MAX + j];
        int a = adj[(size_t)(base + i) * K_MAX + j];
        adj_lds[i * K_MAX + (K_MAX - 1 - j)] = m ? a : DUMMY_NODE;
        h |= m;
      }
    } else {
      for (int j = 0; j < K_MAX; j++) adj_lds[i * K_MAX + j] = DUMMY_NODE;
    }
    hn_lds[i] = (unsigned char)(h ? 1 : 0);
  }

  // ---- prologue: pack this block's LUT slice into LDS ----
  const int nwords = nloc * 64;
  const int* lp = lut + (size_t)base * 4096;
  for (int w0 = wave * 8; w0 < nwords; w0 += 128) {   // 16 waves x 8 words
    int v[8];
#pragma unroll
    for (int q = 0; q < 8; q++) {
      int widx = w0 + q;
      v[q] = (widx < nwords) ? lp[(size_t)widx * 64 + lane] : 0;   // coalesced 256B
    }
#pragma unroll
    for (int q = 0; q < 8; q++) {
      int widx = w0 + q;
      u64 bal = __ballot(v[q] != 0);
      if (lane == 0 && widx < nwords) lut_lds[widx] = bal;
    }
  }
  __syncthreads();   // fence + LDS ready; slot 0 from init (launch-ordered)

  const int l0 = wave * 5;
  const int cnt5 = min(5, nloc - l0);          // <=0 for idle waves
  const int a_reg = (lane < 60) ? adj_lds[l0 * K_MAX + lane] : DUMMY_NODE;
  const bool store_ln = (lane < cnt5);
  const bool myhn = store_ln && hn_lds[l0 + lane];
  u64 mystate = 0;                             // for hn==0 keep-and-republish
  if (store_ln) mystate = (inis[base + l0 + lane] != 0) ? ~0ull : 0ull;

  // ---- 128 steps ----
  for (int s = 0; s < T_STEPS; s++) {
    const u64* slot_cur = ring + (size_t)s * ST_STRIDE;
    u64* slot_nxt      = ring + (size_t)(s + 1) * ST_STRIDE;

    if (cnt5 > 0) {                            // node wave (wave-uniform)
      // gather: PLAIN cached load (write-once addresses; L2 dedupes per XCD)
      u64 w = 0;
      if (lane < 60) {
        const u64* p = (a_reg < N_INPUT) ? (u_all + (size_t)s * 64 + a_reg)
                                         : (slot_cur + a_reg);
        w = *p;
      }
      w = bit_transpose64(w, lane);            // lane b: 60 index bits for batch b

      u64 keep = 0;
#pragma unroll
      for (int i = 0; i < 5; i++) {
        if (i < cnt5) {
          unsigned idx = (unsigned)(w >> (12 * i)) & 0xFFFu;   // MSB-first
          u64 g = lut_lds[(l0 + i) * 64 + (idx >> 6)];
          u64 res = __ballot((g >> (idx & 63)) & 1ull);
          if (lane == i) keep = res;
        }
      }
      if (store_ln) {
        u64 newS = myhn ? keep : mystate;      // no-neigh: keep, republish
        mystate = newS;
        // publish: agent store -> coherence point (consumers plain-load later)
        A_STORE(&slot_nxt[base + l0 + lane], newS);
      }
    }

    // ---- 2-hop all-to-all grid barrier ----
    if (s != T_STEPS - 1) {
      const unsigned tgt = (unsigned)(s + 1) * (NBLK / BAR_N);
      __syncthreads();                         // all waves drain stores to IF
      __builtin_amdgcn_fence(__ATOMIC_RELEASE, "workgroup");  // compiler ordering
      if (tid == 0)
        A_RMW(&arr[bi & (BAR_N - 1)], 1u);     // arrive: one RMW (4 blocks/ctr)
      if (wave == 0) {
        for (;;) {                             // one 64-lane sc1 load per round
          unsigned v = A_LOAD(&arr[lane]);     // lane l -> counter l (4 lines)
          if (__all(v >= tgt)) break;          // monotone: >= is skew-safe
        }
      }
      __builtin_amdgcn_fence(__ATOMIC_ACQUIRE, "workgroup");  // compiler ordering
      __syncthreads();
    }
  }
}

// ------- readout: sigmoid(feats @ W_out^T + b_out) from ring slot 128 -------
__global__ __launch_bounds__(256) void readout_kernel(const u64* __restrict__ st,
                                                      const float* __restrict__ Wout,
                                                      const float* __restrict__ bout,
                                                      float* __restrict__ out) {
  const int b = blockIdx.x / N_OUT;
  const int o = blockIdx.x % N_OUT;
  float acc = 0.f;
  for (int n = threadIdx.x; n < N_FEAT; n += 256) {
    u64 s = st[N_INPUT + n];
    float w = Wout[(size_t)o * N_FEAT + n];
    acc += ((s >> b) & 1ull) ? w : 0.f;
  }
  for (int off = 32; off > 0; off >>= 1) acc += __shfl_down(acc, off);
  __shared__ float red[4];
  const int wave = threadIdx.x >> 6, lane = threadIdx.x & 63;
  if (lane == 0) red[wave] = acc;
  __syncthreads();
  if (threadIdx.x == 0) {
    float tot = red[0] + red[1] + red[2] + red[3] + bout[o];
    out[(size_t)b * N_OUT + o] = 1.f / (1.f + __expf(-tot));
  }
}

extern "C" void kernel_launch(void* const* d_in, const int* in_sizes, int n_in,
                              void* d_out, int out_size, void* d_ws, size_t ws_size,
                              hipStream_t stream) {
  const int* x    = (const int*)d_in[0];
  const int* w_in = (const int*)d_in[1];
  const int* adj  = (const int*)d_in[2];
  const int* mask = (const int*)d_in[3];
  const int* lut  = (const int*)d_in[4];
  const int* inis = (const int*)d_in[5];
  const float* Wout = (const float*)d_in[6];
  const float* bout = (const float*)d_in[7];
  float* out = (float*)d_out;

  char* ws = (char*)d_ws;
  size_t off = 0;
  auto alloc = [&](size_t bytes) -> void* {
    void* p = ws + off;
    off += (bytes + 255) & ~(size_t)255;
    return p;
  };
  u64* ring  = (u64*)alloc((size_t)R_DEPTH * ST_STRIDE * 8);  // 20.65 MB
  u64* xp    = (u64*)alloc((size_t)T_STEPS * N_BATCH * 8);
  u64* wcol  = (u64*)alloc(64 * 8);
  u64* u_all = (u64*)alloc((size_t)T_STEPS * 64 * 8);         // 64 KB
  unsigned* arr = (unsigned*)alloc((size_t)BAR_N * 4);        // 256 B, 4 lines
  (void)ws_size; (void)in_sizes; (void)n_in; (void)out_size;

  hipLaunchKernelGGL(pack_x_kernel, dim3(T_STEPS), dim3(256), 0, stream, x, xp);
  hipLaunchKernelGGL(init_kernel, dim3(80), dim3(256), 0, stream,
                     inis, w_in, ring, wcol, arr);
  hipLaunchKernelGGL(u_pre_kernel, dim3(T_STEPS), dim3(64), 0, stream,
                     xp, wcol, u_all);

  void* args[] = {(void*)&lut, (void*)&adj, (void*)&mask, (void*)&inis,
                  (void*)&u_all, (void*)&ring, (void*)&arr};
  hipLaunchCooperativeKernel((const void*)reservoir_kernel,
                             dim3(NBLK), dim3(NTHR), args, 0, stream);

  // final states live in ring slot 128
  hipLaunchKernelGGL(readout_kernel, dim3(N_BATCH * N_OUT), dim3(256), 0, stream,
                     ring + (size_t)T_STEPS * ST_STRIDE, Wout, bout, out);
}

// Round 10
// 1118.725 us; speedup vs baseline: 1.5662x; 1.5662x over previous
//
#include <hip/hip_runtime.h>
#include <cstdint>
#include <cstddef>

// BooleanReservoir — persistent cooperative kernel, v9 (wave-granular barrier).
// lane = batch; states[node] = u64 (bit b = batch b). Packed LUT + adjacency in
// LDS (read-only after prologue). Never-reused ring (129 padded slots): publish
// = agent-scope store, gather = PLAIN cached load (L2-deduped; R8: FETCH==LUT).
// R10: NO per-step __syncthreads. Each wave: s_waitcnt vmcnt(0) (own stores) ->
// leaf RMW (64 waves/leaf, 64 distinct lines) -> leaf-last promotes to root ->
// root-last 64-lane-stores 64 go lines -> each wave sleeps-polls its go flag.
// Phase safety: a wave arrives for epoch e+1 only after observing go>=e, which
// requires ALL 4096 wave-arrivals for e. R9 lessons: RMW lines disjoint from
// polled lines; all spins s_sleep-throttled.

#define N_NODES   20000
#define N_INPUT   64
#define K_MAX     12
#define T_STEPS   128
#define N_BATCH   64
#define N_OUT     10
#define N_FEAT    (N_NODES - N_INPUT)   // 19936
#define DUMMY_NODE 20000                // always-zero state word
#define ST_STRIDE 20040                 // words/slot + 256B pad (prefetch guard)
#define R_DEPTH   (T_STEPS + 1)         // 129 slots, write-once

#define NBLK 256
#define NTHR 1024                       // 16 waves/block, 1 block/CU
#define NPB  78                         // nodes/block: 256*78 = 19968 >= 19936
#define NPB_PAD 80
#define AS    32                        // barrier slot stride: 32 u32 = 128 B
#define NW_TOT 4096                     // total waves = arrivals per epoch

typedef unsigned long long u64;

#define A_LOAD(p)    __hip_atomic_load((p), __ATOMIC_RELAXED, __HIP_MEMORY_SCOPE_AGENT)
#define A_STORE(p,v) __hip_atomic_store((p), (v), __ATOMIC_RELAXED, __HIP_MEMORY_SCOPE_AGENT)
#define A_RMW(p,v)   __hip_atomic_fetch_add((p), (v), __ATOMIC_RELAXED, __HIP_MEMORY_SCOPE_AGENT)

// ---------------- pack x: xp[t][b] = bits j of x[b][t][j] ----------------
__global__ __launch_bounds__(256) void pack_x_kernel(const int* __restrict__ x,
                                                     u64* __restrict__ xp) {
  const int t = blockIdx.x;
  const int wave = threadIdx.x >> 6, lane = threadIdx.x & 63;
  for (int b = wave; b < N_BATCH; b += 4) {
    int v = x[((size_t)b * T_STEPS + t) * 64 + lane];
    u64 bal = __ballot(v != 0);
    if (lane == 0) xp[(size_t)t * N_BATCH + b] = bal;
  }
}

// ---- init ring slot 0, per-slot dummy words, wcol, leaf/root/go slots ----
__global__ __launch_bounds__(256) void init_kernel(const int* __restrict__ inis,
                                                   const int* __restrict__ w_in,
                                                   u64* __restrict__ ring,
                                                   u64* __restrict__ wcol,
                                                   unsigned* __restrict__ leaf,
                                                   unsigned* __restrict__ root,
                                                   unsigned* __restrict__ go) {
  if (blockIdx.x < 79) {
    int n = blockIdx.x * 256 + threadIdx.x;
    if (n >= N_INPUT && n < N_NODES)
      ring[n] = (inis[n] != 0) ? ~0ull : 0ull;         // slot 0 state
  } else {
    const int wave = threadIdx.x >> 6, lane = threadIdx.x & 63;
    for (int i = wave; i < 64; i += 4) {
      int wv = w_in[(size_t)lane * 64 + i];            // lane = j
      u64 wc = __ballot(wv != 0);
      if (lane == 0) wcol[i] = wc;
    }
    // dummy word (always 0) in every slot; pads never read
    if (threadIdx.x < R_DEPTH)
      ring[(size_t)threadIdx.x * ST_STRIDE + DUMMY_NODE] = 0ull;
    if (threadIdx.x < 64) {                            // ws re-poisoned each call
      leaf[threadIdx.x * AS] = 0u;
      go[threadIdx.x * AS] = 0u;
    }
    if (threadIdx.x == 64) root[0] = 0u;
  }
}

// -------- precompute u(t): u_all[t*64+i] bit b = (xp[t][b] & wcol[i]) != 0 --------
__global__ __launch_bounds__(64) void u_pre_kernel(const u64* __restrict__ xp,
                                                   const u64* __restrict__ wcol,
                                                   u64* __restrict__ u_all) {
  const int t = blockIdx.x, lane = threadIdx.x;
  u64 xw = xp[(size_t)t * N_BATCH + lane];             // lane = batch
  for (int i = 0; i < 64; i++) {
    u64 ub = __ballot((xw & wcol[i]) != 0);
    if (lane == 0) u_all[(size_t)t * 64 + i] = ub;
  }
}

// ---- 64x64 bit transpose: lane l holds row l; returns lane b holding column b ----
__device__ __forceinline__ u64 bit_transpose64(u64 w, int lane) {
  const u64 LO0 = 0x00000000FFFFFFFFull, LO1 = 0x0000FFFF0000FFFFull,
            LO2 = 0x00FF00FF00FF00FFull, LO3 = 0x0F0F0F0F0F0F0F0Full,
            LO4 = 0x3333333333333333ull, LO5 = 0x5555555555555555ull;
#define XP_STAGE(d, LO)                                                  \
  {                                                                      \
    u64 p = (u64)__shfl_xor((long long)w, (d), 64);                      \
    if (lane & (d)) w = ((p >> (d)) & (LO)) | (w & ~(LO));               \
    else            w = (w & (LO)) | ((p << (d)) & ~(LO));               \
  }
  XP_STAGE(32, LO0) XP_STAGE(16, LO1) XP_STAGE(8, LO2)
  XP_STAGE(4,  LO3) XP_STAGE(2,  LO4) XP_STAGE(1, LO5)
#undef XP_STAGE
  return w;
}

// ---------------- persistent reservoir: all 128 steps ----------------
__global__ __launch_bounds__(NTHR) void reservoir_kernel(
    const int* __restrict__ lut, const int* __restrict__ adj,
    const int* __restrict__ mask, const int* __restrict__ inis,
    const u64* __restrict__ u_all, u64* __restrict__ ring,
    unsigned* __restrict__ leaf, unsigned* __restrict__ root,
    unsigned* __restrict__ go) {
  __shared__ u64 lut_lds[NPB_PAD * 64];        // 40960 B
  __shared__ int adj_lds[NPB_PAD * K_MAX];     //  3840 B
  __shared__ unsigned char hn_lds[NPB_PAD];

  const int bi = blockIdx.x;
  const int tid = threadIdx.x;
  const int wave = tid >> 6, lane = tid & 63;
  const int base = N_INPUT + bi * NPB;
  const int nloc = min(NPB, N_NODES - base);   // last block: 46

  // one-time cache scrub: drop poison/stale lines so later PLAIN ring/u_all
  // loads fetch fresh post-publish data (per-step cache ops = R2 disaster;
  // once per block is free).
  if (wave == 0) __builtin_amdgcn_fence(__ATOMIC_ACQUIRE, "agent");

  // ---- prologue: adjacency (slot-REVERSED: slot j at offset 11-j) + hn ----
  if (tid < NPB_PAD) {
    int i = tid, h = 0;
    if (i < nloc) {
      for (int j = 0; j < K_MAX; j++) {
        int m = mask[(size_t)(base + i) * K_MAX + j];
        int a = adj[(size_t)(base + i) * K_MAX + j];
        adj_lds[i * K_MAX + (K_MAX - 1 - j)] = m ? a : DUMMY_NODE;
        h |= m;
      }
    } else {
      for (int j = 0; j < K_MAX; j++) adj_lds[i * K_MAX + j] = DUMMY_NODE;
    }
    hn_lds[i] = (unsigned char)(h ? 1 : 0);
  }

  // ---- prologue: pack this block's LUT slice into LDS ----
  const int nwords = nloc * 64;
  const int* lp = lut + (size_t)base * 4096;
  for (int w0 = wave * 8; w0 < nwords; w0 += 128) {   // 16 waves x 8 words
    int v[8];
#pragma unroll
    for (int q = 0; q < 8; q++) {
      int widx = w0 + q;
      v[q] = (widx < nwords) ? lp[(size_t)widx * 64 + lane] : 0;   // coalesced 256B
    }
#pragma unroll
    for (int q = 0; q < 8; q++) {
      int widx = w0 + q;
      u64 bal = __ballot(v[q] != 0);
      if (lane == 0 && widx < nwords) lut_lds[widx] = bal;
    }
  }
  __syncthreads();   // LDS ready; read-only hereafter. Slot 0: launch-ordered.

  const int l0 = wave * 5;
  const int cnt5 = min(5, nloc - l0);          // <=0 for idle waves
  const int a_reg = (lane < 60) ? adj_lds[l0 * K_MAX + lane] : DUMMY_NODE;
  const bool store_ln = (lane < cnt5);
  const bool myhn = store_ln && hn_lds[l0 + lane];
  u64 mystate = 0;                             // for hn==0 keep-and-republish
  if (store_ln) mystate = (inis[base + l0 + lane] != 0) ? ~0ull : 0ull;

  unsigned* const myleaf = &leaf[(bi & 63) * AS];   // 4 blocks x 16 waves = 64/leaf
  unsigned* const mygo   = &go[(bi & 63) * AS];     // 16 waves poll this line

  // ---- 128 steps; per-wave sync, no __syncthreads in the loop ----
  for (int s = 0; s < T_STEPS; s++) {
    const u64* slot_cur = ring + (size_t)s * ST_STRIDE;
    u64* slot_nxt      = ring + (size_t)(s + 1) * ST_STRIDE;

    if (cnt5 > 0) {                            // node wave (wave-uniform)
      // gather: PLAIN cached load (write-once addresses; L2 dedupes per XCD)
      u64 w = 0;
      if (lane < 60) {
        const u64* p = (a_reg < N_INPUT) ? (u_all + (size_t)s * 64 + a_reg)
                                         : (slot_cur + a_reg);
        w = *p;
      }
      w = bit_transpose64(w, lane);            // lane b: 60 index bits for batch b

      u64 keep = 0;
#pragma unroll
      for (int i = 0; i < 5; i++) {
        if (i < cnt5) {
          unsigned idx = (unsigned)(w >> (12 * i)) & 0xFFFu;   // MSB-first
          u64 g = lut_lds[(l0 + i) * 64 + (idx >> 6)];
          u64 res = __ballot((g >> (idx & 63)) & 1ull);
          if (lane == i) keep = res;
        }
      }
      if (store_ln) {
        u64 newS = myhn ? keep : mystate;      // no-neigh: keep, republish
        mystate = newS;
        A_STORE(&slot_nxt[base + l0 + lane], newS);   // publish -> IF
      }
    }

    // ---- wave-granular barrier ----
    if (s != T_STEPS - 1) {
      const unsigned e = (unsigned)(s + 1);
      const unsigned full = e * 64u;           // 64 arrivals/leaf, 64 leaves/root
      __builtin_amdgcn_s_waitcnt(0x0F70);      // vmcnt(0): MY stores are at IF
      __builtin_amdgcn_fence(__ATOMIC_RELEASE, "workgroup");  // compiler ordering
      unsigned old = 0;
      if (lane == 0) old = A_RMW(myleaf, 1u);  // arrive (wave-granular)
      old = (unsigned)__shfl((int)old, 0);
      if (old == full - 1u) {                  // my wave completed this leaf
        unsigned rold = 0;
        if (lane == 0) rold = A_RMW(root, 1u);
        rold = (unsigned)__shfl((int)rold, 0);
        if (rold == full - 1u)                 // last leaf: release all
          A_STORE(&go[lane * AS], e);          // 64 lanes -> 64 go lines
      }
      int guard = 0;
      while (A_LOAD(mygo) < e) {               // same-addr wave poll, throttled
        __builtin_amdgcn_s_sleep(1);
        if (++guard > (1 << 15)) break;        // fail loud (absmax), never hang
      }
      __builtin_amdgcn_fence(__ATOMIC_ACQUIRE, "workgroup");  // compiler ordering
    }
  }
}

// ------- readout: sigmoid(feats @ W_out^T + b_out) from ring slot 128 -------
__global__ __launch_bounds__(256) void readout_kernel(const u64* __restrict__ st,
                                                      const float* __restrict__ Wout,
                                                      const float* __restrict__ bout,
                                                      float* __restrict__ out) {
  const int b = blockIdx.x / N_OUT;
  const int o = blockIdx.x % N_OUT;
  float acc = 0.f;
  for (int n = threadIdx.x; n < N_FEAT; n += 256) {
    u64 s = st[N_INPUT + n];
    float w = Wout[(size_t)o * N_FEAT + n];
    acc += ((s >> b) & 1ull) ? w : 0.f;
  }
  for (int off = 32; off > 0; off >>= 1) acc += __shfl_down(acc, off);
  __shared__ float red[4];
  const int wave = threadIdx.x >> 6, lane = threadIdx.x & 63;
  if (lane == 0) red[wave] = acc;
  __syncthreads();
  if (threadIdx.x == 0) {
    float tot = red[0] + red[1] + red[2] + red[3] + bout[o];
    out[(size_t)b * N_OUT + o] = 1.f / (1.f + __expf(-tot));
  }
}

extern "C" void kernel_launch(void* const* d_in, const int* in_sizes, int n_in,
                              void* d_out, int out_size, void* d_ws, size_t ws_size,
                              hipStream_t stream) {
  const int* x    = (const int*)d_in[0];
  const int* w_in = (const int*)d_in[1];
  const int* adj  = (const int*)d_in[2];
  const int* mask = (const int*)d_in[3];
  const int* lut  = (const int*)d_in[4];
  const int* inis = (const int*)d_in[5];
  const float* Wout = (const float*)d_in[6];
  const float* bout = (const float*)d_in[7];
  float* out = (float*)d_out;

  char* ws = (char*)d_ws;
  size_t off = 0;
  auto alloc = [&](size_t bytes) -> void* {
    void* p = ws + off;
    off += (bytes + 255) & ~(size_t)255;
    return p;
  };
  u64* ring  = (u64*)alloc((size_t)R_DEPTH * ST_STRIDE * 8);  // 20.7 MB
  u64* xp    = (u64*)alloc((size_t)T_STEPS * N_BATCH * 8);
  u64* wcol  = (u64*)alloc(64 * 8);
  u64* u_all = (u64*)alloc((size_t)T_STEPS * 64 * 8);         // 64 KB
  unsigned* leaf = (unsigned*)alloc((size_t)64 * AS * 4);     // 64 lines
  unsigned* root = (unsigned*)alloc((size_t)AS * 4);          // own line
  unsigned* go   = (unsigned*)alloc((size_t)64 * AS * 4);     // 64 lines
  (void)ws_size; (void)in_sizes; (void)n_in; (void)out_size;

  hipLaunchKernelGGL(pack_x_kernel, dim3(T_STEPS), dim3(256), 0, stream, x, xp);
  hipLaunchKernelGGL(init_kernel, dim3(80), dim3(256), 0, stream,
                     inis, w_in, ring, wcol, leaf, root, go);
  hipLaunchKernelGGL(u_pre_kernel, dim3(T_STEPS), dim3(64), 0, stream,
                     xp, wcol, u_all);

  void* args[] = {(void*)&lut, (void*)&adj, (void*)&mask, (void*)&inis,
                  (void*)&u_all, (void*)&ring, (void*)&leaf, (void*)&root,
                  (void*)&go};
  hipLaunchCooperativeKernel((const void*)reservoir_kernel,
                             dim3(NBLK), dim3(NTHR), args, 0, stream);

  // final states live in ring slot 128
  hipLaunchKernelGGL(readout_kernel, dim3(N_BATCH * N_OUT), dim3(256), 0, stream,
                     ring + (size_t)T_STEPS * ST_STRIDE, Wout, bout, out);
}